// Round 2
// baseline (1966.347 us; speedup 1.0000x reference)
//
#include <hip/hip_runtime.h>
#include <hip/hip_bf16.h>
#include <math.h>

#define HD 128   // hidden dim = H*C
#define NH 4     // heads
#define CC 32    // channels per head

__device__ __forceinline__ float leaky(float x) { return x > 0.f ? x : 0.01f * x; }

// monotone encode of float for unsigned atomicMax
__device__ __forceinline__ unsigned fenc(float f) {
    unsigned u = __float_as_uint(f);
    return (u & 0x80000000u) ? ~u : (u | 0x80000000u);
}
__device__ __forceinline__ float fdec(unsigned u) {
    return (u & 0x80000000u) ? __uint_as_float(u & 0x7fffffffu) : __uint_as_float(~u);
}

// ---------------------------------------------------------------------------
// Fused GEMM: O = X @ W + b for 4 weight matrices (q,k,v,skip), W is 128x128.
// 64 rows/block, 256 threads: thread = (colgroup cg in 0..31 -> 4 cols, rowgroup rg
// in 0..7 -> 8 rows). 32 accumulators/thread, float4 k-unroll.
// ---------------------------------------------------------------------------
__global__ __launch_bounds__(256) void gemm4_128(
    const float* __restrict__ X,
    const float* __restrict__ Wq, const float* __restrict__ Wk,
    const float* __restrict__ Wv, const float* __restrict__ Wsk,
    const float* __restrict__ bq, const float* __restrict__ bk,
    const float* __restrict__ bv, const float* __restrict__ bsk,
    float* __restrict__ Oq, float* __restrict__ Ok,
    float* __restrict__ Ov, float* __restrict__ Osk, int N)
{
    int mat = blockIdx.y;
    const float* W = (mat == 0) ? Wq : (mat == 1) ? Wk : (mat == 2) ? Wv : Wsk;
    const float* b = (mat == 0) ? bq : (mat == 1) ? bk : (mat == 2) ? bv : bsk;
    float* O = (mat == 0) ? Oq : (mat == 1) ? Ok : (mat == 2) ? Ov : Osk;

    int t = threadIdx.x;
    int cg = t & 31;   // columns 4*cg .. 4*cg+3
    int rg = t >> 5;   // 0..7
    int row0 = blockIdx.x * 64 + rg * 8;

    const float* xr[8];
#pragma unroll
    for (int i = 0; i < 8; ++i) {
        int r = row0 + i;
        r = (r < N) ? r : (N - 1);
        xr[i] = X + (size_t)r * HD;
    }

    float acc[8][4];
#pragma unroll
    for (int i = 0; i < 8; ++i)
#pragma unroll
        for (int c = 0; c < 4; ++c) acc[i][c] = 0.f;

    for (int kk = 0; kk < HD; kk += 4) {
        float4 w0 = *(const float4*)(W + (size_t)(kk + 0) * HD + cg * 4);
        float4 w1 = *(const float4*)(W + (size_t)(kk + 1) * HD + cg * 4);
        float4 w2 = *(const float4*)(W + (size_t)(kk + 2) * HD + cg * 4);
        float4 w3 = *(const float4*)(W + (size_t)(kk + 3) * HD + cg * 4);
#pragma unroll
        for (int i = 0; i < 8; ++i) {
            float4 xv = *(const float4*)(xr[i] + kk);
            acc[i][0] += xv.x * w0.x + xv.y * w1.x + xv.z * w2.x + xv.w * w3.x;
            acc[i][1] += xv.x * w0.y + xv.y * w1.y + xv.z * w2.y + xv.w * w3.y;
            acc[i][2] += xv.x * w0.z + xv.y * w1.z + xv.z * w2.z + xv.w * w3.z;
            acc[i][3] += xv.x * w0.w + xv.y * w1.w + xv.z * w2.w + xv.w * w3.w;
        }
    }

    float4 bb = *(const float4*)(b + cg * 4);
#pragma unroll
    for (int i = 0; i < 8; ++i) {
        int r = row0 + i;
        if (r < N) {
            float4 o;
            o.x = acc[i][0] + bb.x;
            o.y = acc[i][1] + bb.y;
            o.z = acc[i][2] + bb.z;
            o.w = acc[i][3] + bb.w;
            *(float4*)(O + (size_t)r * HD + cg * 4) = o;
        }
    }
}

// ---------------------------------------------------------------------------
// One wave per edge: alpha_raw[e][h] = dot(q[dst][h], k[src][h]+e[h]) / sqrt(C)
// + atomicMax of encoded alpha into m[dst][h].
// ---------------------------------------------------------------------------
__global__ __launch_bounds__(256) void edge_alpha(
    const float* __restrict__ q, const float* __restrict__ k,
    const int* __restrict__ ei, const float* __restrict__ ea,
    const float* __restrict__ We, float* __restrict__ alpha,
    unsigned* __restrict__ m, int E)
{
    int wid = (int)((blockIdx.x * 256 + threadIdx.x) >> 6);
    int lane = threadIdx.x & 63;
    if (wid >= E) return;
    int src = ei[wid];
    int dst = ei[E + wid];
    float a0 = ea[2 * wid], a1 = ea[2 * wid + 1];
    int c = lane * 2;
    float2 qv = *(const float2*)(q + (size_t)dst * HD + c);
    float2 kv = *(const float2*)(k + (size_t)src * HD + c);
    float2 e0 = *(const float2*)(We + c);
    float2 e1 = *(const float2*)(We + HD + c);
    float ex = a0 * e0.x + a1 * e1.x;
    float ey = a0 * e0.y + a1 * e1.y;
    float p = qv.x * (kv.x + ex) + qv.y * (kv.y + ey);
    p += __shfl_xor(p, 1);
    p += __shfl_xor(p, 2);
    p += __shfl_xor(p, 4);
    p += __shfl_xor(p, 8);
    if ((lane & 15) == 0) {
        int h = lane >> 4;
        float ar = p * 0.17677669529663687f;  // 1/sqrt(32)
        alpha[(size_t)wid * NH + h] = ar;
        atomicMax(m + (size_t)dst * NH + h, fenc(ar));
    }
}

// ---------------------------------------------------------------------------
// alpha = exp(alpha_raw - m[dst]); denom[dst] += alpha (atomic)
// ---------------------------------------------------------------------------
__global__ __launch_bounds__(256) void edge_exp(
    float* __restrict__ alpha, const unsigned* __restrict__ m,
    float* __restrict__ denom, const int* __restrict__ ei, int E)
{
    int i = blockIdx.x * 256 + threadIdx.x;
    if (i >= E * NH) return;
    int e = i >> 2, h = i & 3;
    int dst = ei[E + e];
    float a = expf(alpha[i] - fdec(m[(size_t)dst * NH + h]));
    alpha[i] = a;
    atomicAdd(denom + (size_t)dst * NH + h, a);
}

// ---------------------------------------------------------------------------
// One wave per edge: agg[dst] += (alpha/denom) * (v[src] + e)   (f32 atomics)
// ---------------------------------------------------------------------------
__global__ __launch_bounds__(256) void edge_msg(
    const float* __restrict__ v, const float* __restrict__ alpha,
    const float* __restrict__ denom, const int* __restrict__ ei,
    const float* __restrict__ ea, const float* __restrict__ We,
    float* __restrict__ agg, int E)
{
    int wid = (int)((blockIdx.x * 256 + threadIdx.x) >> 6);
    int lane = threadIdx.x & 63;
    if (wid >= E) return;
    int src = ei[wid];
    int dst = ei[E + wid];
    float a0 = ea[2 * wid], a1 = ea[2 * wid + 1];
    int c = lane * 2;
    int h = lane >> 4;
    float al = alpha[(size_t)wid * NH + h];
    float den = denom[(size_t)dst * NH + h];
    float coef = al / (den + 1e-16f);
    float2 vv = *(const float2*)(v + (size_t)src * HD + c);
    float2 e0 = *(const float2*)(We + c);
    float2 e1 = *(const float2*)(We + HD + c);
    float ex = a0 * e0.x + a1 * e1.x;
    float ey = a0 * e0.y + a1 * e1.y;
    atomicAdd(agg + (size_t)dst * HD + c, coef * (vv.x + ex));
    atomicAdd(agg + (size_t)dst * HD + c + 1, coef * (vv.y + ey));
}

// ---------------------------------------------------------------------------
// h = leaky(agg + skip)
// ---------------------------------------------------------------------------
__global__ __launch_bounds__(256) void finalize_layer(
    const float* __restrict__ agg, const float* __restrict__ s,
    float* __restrict__ h, int n4)
{
    int i = blockIdx.x * 256 + threadIdx.x;
    if (i >= n4) return;
    float4 a = ((const float4*)agg)[i];
    float4 sk = ((const float4*)s)[i];
    float4 o;
    o.x = leaky(a.x + sk.x);
    o.y = leaky(a.y + sk.y);
    o.z = leaky(a.z + sk.z);
    o.w = leaky(a.w + sk.w);
    ((float4*)h)[i] = o;
}

// ---------------------------------------------------------------------------
// emb = leaky(h @ W1 + b1)   (N x 128 @ 128 x 32)
// ---------------------------------------------------------------------------
__global__ __launch_bounds__(256) void emb_kernel(
    const float* __restrict__ h, const float* __restrict__ W1,
    const float* __restrict__ b1, float* __restrict__ emb, int N)
{
    int i = blockIdx.x * 256 + threadIdx.x;
    if (i >= N * CC) return;
    int row = i >> 5, col = i & 31;
    const float* hr = h + (size_t)row * HD;
    float acc = 0.f;
#pragma unroll 4
    for (int k = 0; k < HD; ++k) acc += hr[k] * W1[k * CC + col];
    emb[i] = leaky(acc + b1[col]);
}

// ---------------------------------------------------------------------------
// logits = emb @ W2 + b2; out = log_softmax(logits) per row (8 cols).
// 8 lanes per row.
// ---------------------------------------------------------------------------
__global__ __launch_bounds__(256) void logits_kernel(
    const float* __restrict__ emb, const float* __restrict__ W2,
    const float* __restrict__ b2, float* __restrict__ out, int N)
{
    int i = blockIdx.x * 256 + threadIdx.x;
    int row = i >> 3, col = i & 7;
    if (row >= N) return;
    const float* er = emb + (size_t)row * CC;
    float acc = b2[col];
#pragma unroll
    for (int k = 0; k < CC; ++k) acc += er[k] * W2[k * 8 + col];
    float mx = acc;
    mx = fmaxf(mx, __shfl_xor(mx, 1));
    mx = fmaxf(mx, __shfl_xor(mx, 2));
    mx = fmaxf(mx, __shfl_xor(mx, 4));
    float ex = expf(acc - mx);
    float sm = ex;
    sm += __shfl_xor(sm, 1);
    sm += __shfl_xor(sm, 2);
    sm += __shfl_xor(sm, 4);
    out[i] = acc - mx - logf(sm);
}

extern "C" void kernel_launch(void* const* d_in, const int* in_sizes, int n_in,
                              void* d_out, int out_size, void* d_ws, size_t ws_size,
                              hipStream_t stream)
{
    const float* x  = (const float*)d_in[0];
    const int*   ei = (const int*)d_in[1];
    const float* ea = (const float*)d_in[2];
    const float* Wq = (const float*)d_in[3];
    const float* bq = (const float*)d_in[4];
    const float* Wk = (const float*)d_in[5];
    const float* bk = (const float*)d_in[6];
    const float* Wv = (const float*)d_in[7];
    const float* bv = (const float*)d_in[8];
    const float* We = (const float*)d_in[9];
    const float* Ws = (const float*)d_in[10];
    const float* bs = (const float*)d_in[11];
    const float* W1 = (const float*)d_in[12];
    const float* b1 = (const float*)d_in[13];
    const float* W2 = (const float*)d_in[14];
    const float* b2 = (const float*)d_in[15];

    int N = in_sizes[0] / HD;
    int E = in_sizes[1] / 2;

    float* ws = (float*)d_ws;
    size_t nd = (size_t)N * HD;
    float* hbuf  = ws;
    float* qbuf  = ws + nd;       // aliased as agg after edge_alpha
    float* kbuf  = ws + 2 * nd;
    float* vbuf  = ws + 3 * nd;
    float* sbuf  = ws + 4 * nd;
    float* alpha = ws + 5 * nd;
    unsigned* mb = (unsigned*)(alpha + (size_t)E * NH);
    float* denom = (float*)(mb + (size_t)N * NH);

    int gemm_gx = (N + 63) / 64;
    int edge_gx = (E + 3) / 4;

    for (int l = 0; l < 3; ++l) {
        const float* cur = (l == 0) ? x : hbuf;
        const float* Wel = We + (size_t)l * 2 * HD;

        // zero m (encoded max) and denom — both all-zero bit patterns, contiguous
        hipMemsetAsync(mb, 0, (size_t)N * NH * 2 * sizeof(float), stream);

        gemm4_128<<<dim3(gemm_gx, 4), 256, 0, stream>>>(
            cur,
            Wq + (size_t)l * HD * HD, Wk + (size_t)l * HD * HD,
            Wv + (size_t)l * HD * HD, Ws + (size_t)l * HD * HD,
            bq + (size_t)l * HD, bk + (size_t)l * HD,
            bv + (size_t)l * HD, bs + (size_t)l * HD,
            qbuf, kbuf, vbuf, sbuf, N);

        edge_alpha<<<edge_gx, 256, 0, stream>>>(qbuf, kbuf, ei, ea, Wel, alpha, mb, E);

        edge_exp<<<(E * NH + 255) / 256, 256, 0, stream>>>(alpha, mb, denom, ei, E);

        // q dead now; reuse as aggregation buffer
        hipMemsetAsync(qbuf, 0, nd * sizeof(float), stream);

        edge_msg<<<edge_gx, 256, 0, stream>>>(vbuf, alpha, denom, ei, ea, Wel, qbuf, E);

        finalize_layer<<<(int)((nd / 4 + 255) / 256), 256, 0, stream>>>(qbuf, sbuf, hbuf, (int)(nd / 4));
    }

    // head: emb = leaky(h@W1+b1) -> reuse kbuf; logits+log_softmax -> d_out
    emb_kernel<<<(N * CC + 255) / 256, 256, 0, stream>>>(hbuf, W1, b1, kbuf, N);
    logits_kernel<<<(N * 8 + 255) / 256, 256, 0, stream>>>(kbuf, W2, b2, (float*)d_out, N);
}

// Round 3
// 940.461 us; speedup vs baseline: 2.0908x; 2.0908x over previous
//
#include <hip/hip_runtime.h>
#include <hip/hip_bf16.h>
#include <math.h>

#define HD 128   // hidden dim = H*C
#define NH 4     // heads
#define CC 32    // channels per head

__device__ __forceinline__ float leaky(float x) { return x > 0.f ? x : 0.01f * x; }

// ---------------------------------------------------------------------------
// Fused GEMM: O = X @ W + b for 4 weight matrices (q,k,v,skip), W is 128x128.
// 64 rows/block, 256 threads. 32 accumulators/thread, float4 k-unroll.
// ---------------------------------------------------------------------------
__global__ __launch_bounds__(256) void gemm4_128(
    const float* __restrict__ X,
    const float* __restrict__ Wq, const float* __restrict__ Wk,
    const float* __restrict__ Wv, const float* __restrict__ Wsk,
    const float* __restrict__ bq, const float* __restrict__ bk,
    const float* __restrict__ bv, const float* __restrict__ bsk,
    float* __restrict__ Oq, float* __restrict__ Ok,
    float* __restrict__ Ov, float* __restrict__ Osk, int N)
{
    int mat = blockIdx.y;
    const float* W = (mat == 0) ? Wq : (mat == 1) ? Wk : (mat == 2) ? Wv : Wsk;
    const float* b = (mat == 0) ? bq : (mat == 1) ? bk : (mat == 2) ? bv : bsk;
    float* O = (mat == 0) ? Oq : (mat == 1) ? Ok : (mat == 2) ? Ov : Osk;

    int t = threadIdx.x;
    int cg = t & 31;   // columns 4*cg .. 4*cg+3
    int rg = t >> 5;   // 0..7
    int row0 = blockIdx.x * 64 + rg * 8;

    const float* xr[8];
#pragma unroll
    for (int i = 0; i < 8; ++i) {
        int r = row0 + i;
        r = (r < N) ? r : (N - 1);
        xr[i] = X + (size_t)r * HD;
    }

    float acc[8][4];
#pragma unroll
    for (int i = 0; i < 8; ++i)
#pragma unroll
        for (int c = 0; c < 4; ++c) acc[i][c] = 0.f;

    for (int kk = 0; kk < HD; kk += 4) {
        float4 w0 = *(const float4*)(W + (size_t)(kk + 0) * HD + cg * 4);
        float4 w1 = *(const float4*)(W + (size_t)(kk + 1) * HD + cg * 4);
        float4 w2 = *(const float4*)(W + (size_t)(kk + 2) * HD + cg * 4);
        float4 w3 = *(const float4*)(W + (size_t)(kk + 3) * HD + cg * 4);
#pragma unroll
        for (int i = 0; i < 8; ++i) {
            float4 xv = *(const float4*)(xr[i] + kk);
            acc[i][0] += xv.x * w0.x + xv.y * w1.x + xv.z * w2.x + xv.w * w3.x;
            acc[i][1] += xv.x * w0.y + xv.y * w1.y + xv.z * w2.y + xv.w * w3.y;
            acc[i][2] += xv.x * w0.z + xv.y * w1.z + xv.z * w2.z + xv.w * w3.z;
            acc[i][3] += xv.x * w0.w + xv.y * w1.w + xv.z * w2.w + xv.w * w3.w;
        }
    }

    float4 bb = *(const float4*)(b + cg * 4);
#pragma unroll
    for (int i = 0; i < 8; ++i) {
        int r = row0 + i;
        if (r < N) {
            float4 o;
            o.x = acc[i][0] + bb.x;
            o.y = acc[i][1] + bb.y;
            o.z = acc[i][2] + bb.z;
            o.w = acc[i][3] + bb.w;
            *(float4*)(O + (size_t)r * HD + cg * 4) = o;
        }
    }
}

// ---------------------------------------------------------------------------
// CSR build step 1: deg[dst]++ per edge
// ---------------------------------------------------------------------------
__global__ __launch_bounds__(256) void count_deg(
    const int* __restrict__ ei, int* __restrict__ deg, int E)
{
    int e = blockIdx.x * 256 + threadIdx.x;
    if (e < E) atomicAdd(&deg[ei[E + e]], 1);
}

// ---------------------------------------------------------------------------
// CSR build step 2: exclusive scan of deg -> off (N+1), duplicate into cursor.
// Single block, 1024 threads; per-wave shfl scan + cross-wave LDS combine.
// ---------------------------------------------------------------------------
__global__ __launch_bounds__(1024) void scan_kernel(
    const int* __restrict__ deg, int* __restrict__ off,
    int* __restrict__ cursor, int N)
{
    __shared__ int wsum[16];
    __shared__ int carry_s;
    int tid = threadIdx.x;
    int lane = tid & 63;
    int w = tid >> 6;
    if (tid == 0) carry_s = 0;
    __syncthreads();
    for (int base = 0; base < N; base += 1024) {
        int idx = base + tid;
        int x = (idx < N) ? deg[idx] : 0;
        int val = x;
#pragma unroll
        for (int s = 1; s < 64; s <<= 1) {
            int t = __shfl_up(val, s);
            if (lane >= s) val += t;
        }
        if (lane == 63) wsum[w] = val;
        __syncthreads();
        if (w == 0) {
            int t = (lane < 16) ? wsum[lane] : 0;
#pragma unroll
            for (int s = 1; s < 16; s <<= 1) {
                int u = __shfl_up(t, s);
                if (lane >= s) t += u;
            }
            if (lane < 16) wsum[lane] = t;  // inclusive wave totals
        }
        __syncthreads();
        int carry = carry_s;
        int wexcl = (w > 0) ? wsum[w - 1] : 0;
        int excl = carry + wexcl + (val - x);
        if (idx < N) { off[idx] = excl; cursor[idx] = excl; }
        __syncthreads();
        if (tid == 0) carry_s = carry + wsum[15];
        __syncthreads();
    }
    if (threadIdx.x == 0) off[N] = carry_s;
}

// ---------------------------------------------------------------------------
// CSR build step 3: scatter edge meta {src, ea0, ea1} into dst-grouped slots
// ---------------------------------------------------------------------------
__global__ __launch_bounds__(256) void scatter_edges(
    const int* __restrict__ ei, const float* __restrict__ ea,
    int* __restrict__ cursor, float4* __restrict__ meta, int E)
{
    int e = blockIdx.x * 256 + threadIdx.x;
    if (e >= E) return;
    int dst = ei[E + e];
    int pos = atomicAdd(&cursor[dst], 1);
    meta[pos] = make_float4(__int_as_float(ei[e]), ea[2 * e], ea[2 * e + 1], 0.f);
}

// ---------------------------------------------------------------------------
// Flash-style fused attention: one wave per dst node. Online softmax over the
// node's incoming edges; no atomics, no alpha materialization. Epilogue fuses
// skip + leakyReLU. lane -> 2 channels (c = 2*lane), head = lane>>4.
// ---------------------------------------------------------------------------
__global__ __launch_bounds__(256) void fused_attn(
    const float* __restrict__ q, const float* __restrict__ k,
    const float* __restrict__ v, const float* __restrict__ skip,
    const int* __restrict__ off, const float4* __restrict__ meta,
    const float* __restrict__ We, float* __restrict__ hout, int N)
{
    int wid = (int)((blockIdx.x * 256 + threadIdx.x) >> 6);  // dst node
    int lane = threadIdx.x & 63;
    if (wid >= N) return;
    int c = lane * 2;

    float2 w0 = *(const float2*)(We + c);        // We row 0, this lane's 2 cols
    float2 w1 = *(const float2*)(We + HD + c);   // We row 1
    float2 q2 = *(const float2*)(q + (size_t)wid * HD + c);

    float m = -INFINITY, s = 0.f;
    float ox = 0.f, oy = 0.f;

    int beg = off[wid], end = off[wid + 1];
    for (int j = beg; j < end; ++j) {
        float4 md = meta[j];                      // broadcast (uniform addr)
        int src = __float_as_int(md.x);
        float ex = md.y * w0.x + md.z * w1.x;
        float ey = md.y * w0.y + md.z * w1.y;
        float2 kv = *(const float2*)(k + (size_t)src * HD + c);
        float2 vv = *(const float2*)(v + (size_t)src * HD + c);
        float p = q2.x * (kv.x + ex) + q2.y * (kv.y + ey);
        p += __shfl_xor(p, 1);
        p += __shfl_xor(p, 2);
        p += __shfl_xor(p, 4);
        p += __shfl_xor(p, 8);
        p *= 0.17677669529663687f;               // 1/sqrt(32)
        float mn = fmaxf(m, p);
        float scale = __expf(m - mn);            // first iter: exp(-inf)=0
        float pe = __expf(p - mn);
        s = s * scale + pe;
        ox = ox * scale + pe * (vv.x + ex);
        oy = oy * scale + pe * (vv.y + ey);
        m = mn;
    }

    float inv = 1.f / (s + 1e-16f);              // deg==0: o=0 -> skip only
    float2 sk = *(const float2*)(skip + (size_t)wid * HD + c);
    float2 hv;
    hv.x = leaky(ox * inv + sk.x);
    hv.y = leaky(oy * inv + sk.y);
    *(float2*)(hout + (size_t)wid * HD + c) = hv;
}

// ---------------------------------------------------------------------------
// emb = leaky(h @ W1 + b1)   (N x 128 @ 128 x 32)
// ---------------------------------------------------------------------------
__global__ __launch_bounds__(256) void emb_kernel(
    const float* __restrict__ h, const float* __restrict__ W1,
    const float* __restrict__ b1, float* __restrict__ emb, int N)
{
    int i = blockIdx.x * 256 + threadIdx.x;
    if (i >= N * CC) return;
    int row = i >> 5, col = i & 31;
    const float* hr = h + (size_t)row * HD;
    float acc = 0.f;
#pragma unroll 4
    for (int k = 0; k < HD; ++k) acc += hr[k] * W1[k * CC + col];
    emb[i] = leaky(acc + b1[col]);
}

// ---------------------------------------------------------------------------
// logits = emb @ W2 + b2; out = log_softmax(logits) per row (8 cols).
// ---------------------------------------------------------------------------
__global__ __launch_bounds__(256) void logits_kernel(
    const float* __restrict__ emb, const float* __restrict__ W2,
    const float* __restrict__ b2, float* __restrict__ out, int N)
{
    int i = blockIdx.x * 256 + threadIdx.x;
    int row = i >> 3, col = i & 7;
    if (row >= N) return;
    const float* er = emb + (size_t)row * CC;
    float acc = b2[col];
#pragma unroll
    for (int k = 0; k < CC; ++k) acc += er[k] * W2[k * 8 + col];
    float mx = acc;
    mx = fmaxf(mx, __shfl_xor(mx, 1));
    mx = fmaxf(mx, __shfl_xor(mx, 2));
    mx = fmaxf(mx, __shfl_xor(mx, 4));
    float ex = expf(acc - mx);
    float sm = ex;
    sm += __shfl_xor(sm, 1);
    sm += __shfl_xor(sm, 2);
    sm += __shfl_xor(sm, 4);
    out[i] = acc - mx - logf(sm);
}

extern "C" void kernel_launch(void* const* d_in, const int* in_sizes, int n_in,
                              void* d_out, int out_size, void* d_ws, size_t ws_size,
                              hipStream_t stream)
{
    const float* x  = (const float*)d_in[0];
    const int*   ei = (const int*)d_in[1];
    const float* ea = (const float*)d_in[2];
    const float* Wq = (const float*)d_in[3];
    const float* bq = (const float*)d_in[4];
    const float* Wk = (const float*)d_in[5];
    const float* bk = (const float*)d_in[6];
    const float* Wv = (const float*)d_in[7];
    const float* bv = (const float*)d_in[8];
    const float* We = (const float*)d_in[9];
    const float* Ws = (const float*)d_in[10];
    const float* bs = (const float*)d_in[11];
    const float* W1 = (const float*)d_in[12];
    const float* b1 = (const float*)d_in[13];
    const float* W2 = (const float*)d_in[14];
    const float* b2 = (const float*)d_in[15];

    int N = in_sizes[0] / HD;
    int E = in_sizes[1] / 2;

    float* ws = (float*)d_ws;
    size_t nd = (size_t)N * HD;
    float* hbuf = ws;
    float* qbuf = ws + nd;
    float* kbuf = ws + 2 * nd;
    float* vbuf = ws + 3 * nd;
    float* sbuf = ws + 4 * nd;
    float4* meta = (float4*)(ws + 5 * nd);           // E float4
    int* deg    = (int*)(ws + 5 * nd + 4 * (size_t)E);
    int* off    = deg + N;                            // N+1
    int* cursor = off + N + 1;                        // N

    int gemm_gx = (N + 63) / 64;
    int edge_gx = (E + 255) / 256;
    int attn_gx = (N + 3) / 4;

    // ---- CSR build (once per call) ----
    hipMemsetAsync(deg, 0, (size_t)N * sizeof(int), stream);
    count_deg<<<edge_gx, 256, 0, stream>>>(ei, deg, E);
    scan_kernel<<<1, 1024, 0, stream>>>(deg, off, cursor, N);
    scatter_edges<<<edge_gx, 256, 0, stream>>>(ei, ea, cursor, meta, E);

    for (int l = 0; l < 3; ++l) {
        const float* cur = (l == 0) ? x : hbuf;
        const float* Wel = We + (size_t)l * 2 * HD;

        gemm4_128<<<dim3(gemm_gx, 4), 256, 0, stream>>>(
            cur,
            Wq + (size_t)l * HD * HD, Wk + (size_t)l * HD * HD,
            Wv + (size_t)l * HD * HD, Ws + (size_t)l * HD * HD,
            bq + (size_t)l * HD, bk + (size_t)l * HD,
            bv + (size_t)l * HD, bs + (size_t)l * HD,
            qbuf, kbuf, vbuf, sbuf, N);

        fused_attn<<<attn_gx, 256, 0, stream>>>(
            qbuf, kbuf, vbuf, sbuf, off, meta, Wel, hbuf, N);
    }

    // head: emb = leaky(h@W1+b1) -> reuse kbuf; logits+log_softmax -> d_out
    emb_kernel<<<(N * CC + 255) / 256, 256, 0, stream>>>(hbuf, W1, b1, kbuf, N);
    logits_kernel<<<(N * 8 + 255) / 256, 256, 0, stream>>>(kbuf, W2, b2, (float*)d_out, N);
}

// Round 4
// 778.899 us; speedup vs baseline: 2.5245x; 1.2074x over previous
//
#include <hip/hip_runtime.h>
#include <hip/hip_bf16.h>
#include <math.h>

#define HD 128   // hidden dim = H*C
#define NH 4     // heads
#define CC 32    // channels per head

__device__ __forceinline__ float leaky(float x) { return x > 0.f ? x : 0.01f * x; }

// ---------------------------------------------------------------------------
// Fused GEMM: O = X @ W + b for 4 weight matrices (q,k,v,skip), W is 128x128.
// 64 rows/block, 256 threads. X tile staged in LDS (32 KB) via coalesced
// float4 loads; inner loop reads X as LDS broadcasts (same addr per
// half-wave -> conflict-free), W from global (L1-resident). unroll-2 lets the
// scheduler overlap next-iter W loads with current FMAs.
// ---------------------------------------------------------------------------
__global__ __launch_bounds__(256) void gemm4_128(
    const float* __restrict__ X,
    const float* __restrict__ Wq, const float* __restrict__ Wk,
    const float* __restrict__ Wv, const float* __restrict__ Wsk,
    const float* __restrict__ bq, const float* __restrict__ bk,
    const float* __restrict__ bv, const float* __restrict__ bsk,
    float* __restrict__ Oq, float* __restrict__ Ok,
    float* __restrict__ Ov, float* __restrict__ Osk, int N)
{
    __shared__ float Xs[64 * HD];

    int mat = blockIdx.y;
    const float* W = (mat == 0) ? Wq : (mat == 1) ? Wk : (mat == 2) ? Wv : Wsk;
    const float* b = (mat == 0) ? bq : (mat == 1) ? bk : (mat == 2) ? bv : bsk;
    float* O = (mat == 0) ? Oq : (mat == 1) ? Ok : (mat == 2) ? Ov : Osk;

    int t = threadIdx.x;
    int row0 = blockIdx.x * 64;

    // ---- stage X tile: 64 rows x 128 cols = 2048 float4 / 256 threads ----
#pragma unroll
    for (int i = 0; i < 8; ++i) {
        int idx = t + i * 256;           // 0..2047
        int r = idx >> 5;                // 0..63
        int c4 = (idx & 31) * 4;
        int gr = row0 + r;
        float4 xv = (gr < N) ? *(const float4*)(X + (size_t)gr * HD + c4)
                             : make_float4(0.f, 0.f, 0.f, 0.f);
        *(float4*)(&Xs[r * HD + c4]) = xv;
    }
    __syncthreads();

    int cg = t & 31;   // columns 4*cg .. 4*cg+3
    int rg = t >> 5;   // 0..7 -> rows rg*8 .. rg*8+7
    const float* xb = &Xs[rg * 8 * HD];

    float acc[8][4];
#pragma unroll
    for (int i = 0; i < 8; ++i)
#pragma unroll
        for (int c = 0; c < 4; ++c) acc[i][c] = 0.f;

#pragma unroll 2
    for (int kk = 0; kk < HD; kk += 4) {
        float4 w0 = *(const float4*)(W + (size_t)(kk + 0) * HD + cg * 4);
        float4 w1 = *(const float4*)(W + (size_t)(kk + 1) * HD + cg * 4);
        float4 w2 = *(const float4*)(W + (size_t)(kk + 2) * HD + cg * 4);
        float4 w3 = *(const float4*)(W + (size_t)(kk + 3) * HD + cg * 4);
#pragma unroll
        for (int i = 0; i < 8; ++i) {
            float4 xv = *(const float4*)(xb + i * HD + kk);
            acc[i][0] += xv.x * w0.x + xv.y * w1.x + xv.z * w2.x + xv.w * w3.x;
            acc[i][1] += xv.x * w0.y + xv.y * w1.y + xv.z * w2.y + xv.w * w3.y;
            acc[i][2] += xv.x * w0.z + xv.y * w1.z + xv.z * w2.z + xv.w * w3.z;
            acc[i][3] += xv.x * w0.w + xv.y * w1.w + xv.z * w2.w + xv.w * w3.w;
        }
    }

    float4 bb = *(const float4*)(b + cg * 4);
#pragma unroll
    for (int i = 0; i < 8; ++i) {
        int r = row0 + rg * 8 + i;
        if (r < N) {
            float4 o;
            o.x = acc[i][0] + bb.x;
            o.y = acc[i][1] + bb.y;
            o.z = acc[i][2] + bb.z;
            o.w = acc[i][3] + bb.w;
            *(float4*)(O + (size_t)r * HD + cg * 4) = o;
        }
    }
}

// ---------------------------------------------------------------------------
// CSR build step 1: deg[dst]++ per edge
// ---------------------------------------------------------------------------
__global__ __launch_bounds__(256) void count_deg(
    const int* __restrict__ ei, int* __restrict__ deg, int E)
{
    int e = blockIdx.x * 256 + threadIdx.x;
    if (e < E) atomicAdd(&deg[ei[E + e]], 1);
}

// ---------------------------------------------------------------------------
// CSR build step 2: exclusive scan of deg -> off (N+1), duplicate into cursor.
// ---------------------------------------------------------------------------
__global__ __launch_bounds__(1024) void scan_kernel(
    const int* __restrict__ deg, int* __restrict__ off,
    int* __restrict__ cursor, int N)
{
    __shared__ int wsum[16];
    __shared__ int carry_s;
    int tid = threadIdx.x;
    int lane = tid & 63;
    int w = tid >> 6;
    if (tid == 0) carry_s = 0;
    __syncthreads();
    for (int base = 0; base < N; base += 1024) {
        int idx = base + tid;
        int x = (idx < N) ? deg[idx] : 0;
        int val = x;
#pragma unroll
        for (int s = 1; s < 64; s <<= 1) {
            int t = __shfl_up(val, s);
            if (lane >= s) val += t;
        }
        if (lane == 63) wsum[w] = val;
        __syncthreads();
        if (w == 0) {
            int t = (lane < 16) ? wsum[lane] : 0;
#pragma unroll
            for (int s = 1; s < 16; s <<= 1) {
                int u = __shfl_up(t, s);
                if (lane >= s) t += u;
            }
            if (lane < 16) wsum[lane] = t;  // inclusive wave totals
        }
        __syncthreads();
        int carry = carry_s;
        int wexcl = (w > 0) ? wsum[w - 1] : 0;
        int excl = carry + wexcl + (val - x);
        if (idx < N) { off[idx] = excl; cursor[idx] = excl; }
        __syncthreads();
        if (tid == 0) carry_s = carry + wsum[15];
        __syncthreads();
    }
    if (threadIdx.x == 0) off[N] = carry_s;
}

// ---------------------------------------------------------------------------
// CSR build step 3: scatter edge meta {src, ea0, ea1} into dst-grouped slots
// ---------------------------------------------------------------------------
__global__ __launch_bounds__(256) void scatter_edges(
    const int* __restrict__ ei, const float* __restrict__ ea,
    int* __restrict__ cursor, float4* __restrict__ meta, int E)
{
    int e = blockIdx.x * 256 + threadIdx.x;
    if (e >= E) return;
    int dst = ei[E + e];
    int pos = atomicAdd(&cursor[dst], 1);
    meta[pos] = make_float4(__int_as_float(ei[e]), ea[2 * e], ea[2 * e + 1], 0.f);
}

// ---------------------------------------------------------------------------
// Flash-style fused attention: one wave per dst node. Online softmax over the
// node's incoming edges; no atomics, no alpha materialization. Epilogue fuses
// skip + leakyReLU. lane -> 2 channels (c = 2*lane), head = lane>>4.
// ---------------------------------------------------------------------------
__global__ __launch_bounds__(256) void fused_attn(
    const float* __restrict__ q, const float* __restrict__ k,
    const float* __restrict__ v, const float* __restrict__ skip,
    const int* __restrict__ off, const float4* __restrict__ meta,
    const float* __restrict__ We, float* __restrict__ hout, int N)
{
    int wid = (int)((blockIdx.x * 256 + threadIdx.x) >> 6);  // dst node
    int lane = threadIdx.x & 63;
    if (wid >= N) return;
    int c = lane * 2;

    float2 w0 = *(const float2*)(We + c);        // We row 0, this lane's 2 cols
    float2 w1 = *(const float2*)(We + HD + c);   // We row 1
    float2 q2 = *(const float2*)(q + (size_t)wid * HD + c);

    float m = -INFINITY, s = 0.f;
    float ox = 0.f, oy = 0.f;

    int beg = off[wid], end = off[wid + 1];
    for (int j = beg; j < end; ++j) {
        float4 md = meta[j];                      // broadcast (uniform addr)
        int src = __float_as_int(md.x);
        float ex = md.y * w0.x + md.z * w1.x;
        float ey = md.y * w0.y + md.z * w1.y;
        float2 kv = *(const float2*)(k + (size_t)src * HD + c);
        float2 vv = *(const float2*)(v + (size_t)src * HD + c);
        float p = q2.x * (kv.x + ex) + q2.y * (kv.y + ey);
        p += __shfl_xor(p, 1);
        p += __shfl_xor(p, 2);
        p += __shfl_xor(p, 4);
        p += __shfl_xor(p, 8);
        p *= 0.17677669529663687f;               // 1/sqrt(32)
        float mn = fmaxf(m, p);
        float scale = __expf(m - mn);            // first iter: exp(-inf)=0
        float pe = __expf(p - mn);
        s = s * scale + pe;
        ox = ox * scale + pe * (vv.x + ex);
        oy = oy * scale + pe * (vv.y + ey);
        m = mn;
    }

    float inv = 1.f / (s + 1e-16f);              // deg==0: o=0 -> skip only
    float2 sk = *(const float2*)(skip + (size_t)wid * HD + c);
    float2 hv;
    hv.x = leaky(ox * inv + sk.x);
    hv.y = leaky(oy * inv + sk.y);
    *(float2*)(hout + (size_t)wid * HD + c) = hv;
}

// ---------------------------------------------------------------------------
// emb = leaky(h @ W1 + b1)   (N x 128 @ 128 x 32)
// ---------------------------------------------------------------------------
__global__ __launch_bounds__(256) void emb_kernel(
    const float* __restrict__ h, const float* __restrict__ W1,
    const float* __restrict__ b1, float* __restrict__ emb, int N)
{
    int i = blockIdx.x * 256 + threadIdx.x;
    if (i >= N * CC) return;
    int row = i >> 5, col = i & 31;
    const float* hr = h + (size_t)row * HD;
    float acc = 0.f;
#pragma unroll 4
    for (int k = 0; k < HD; ++k) acc += hr[k] * W1[k * CC + col];
    emb[i] = leaky(acc + b1[col]);
}

// ---------------------------------------------------------------------------
// logits = emb @ W2 + b2; out = log_softmax(logits) per row (8 cols).
// ---------------------------------------------------------------------------
__global__ __launch_bounds__(256) void logits_kernel(
    const float* __restrict__ emb, const float* __restrict__ W2,
    const float* __restrict__ b2, float* __restrict__ out, int N)
{
    int i = blockIdx.x * 256 + threadIdx.x;
    int row = i >> 3, col = i & 7;
    if (row >= N) return;
    const float* er = emb + (size_t)row * CC;
    float acc = b2[col];
#pragma unroll
    for (int k = 0; k < CC; ++k) acc += er[k] * W2[k * 8 + col];
    float mx = acc;
    mx = fmaxf(mx, __shfl_xor(mx, 1));
    mx = fmaxf(mx, __shfl_xor(mx, 2));
    mx = fmaxf(mx, __shfl_xor(mx, 4));
    float ex = expf(acc - mx);
    float sm = ex;
    sm += __shfl_xor(sm, 1);
    sm += __shfl_xor(sm, 2);
    sm += __shfl_xor(sm, 4);
    out[i] = acc - mx - logf(sm);
}

extern "C" void kernel_launch(void* const* d_in, const int* in_sizes, int n_in,
                              void* d_out, int out_size, void* d_ws, size_t ws_size,
                              hipStream_t stream)
{
    const float* x  = (const float*)d_in[0];
    const int*   ei = (const int*)d_in[1];
    const float* ea = (const float*)d_in[2];
    const float* Wq = (const float*)d_in[3];
    const float* bq = (const float*)d_in[4];
    const float* Wk = (const float*)d_in[5];
    const float* bk = (const float*)d_in[6];
    const float* Wv = (const float*)d_in[7];
    const float* bv = (const float*)d_in[8];
    const float* We = (const float*)d_in[9];
    const float* Ws = (const float*)d_in[10];
    const float* bs = (const float*)d_in[11];
    const float* W1 = (const float*)d_in[12];
    const float* b1 = (const float*)d_in[13];
    const float* W2 = (const float*)d_in[14];
    const float* b2 = (const float*)d_in[15];

    int N = in_sizes[0] / HD;
    int E = in_sizes[1] / 2;

    float* ws = (float*)d_ws;
    size_t nd = (size_t)N * HD;
    float* hbuf = ws;
    float* qbuf = ws + nd;
    float* kbuf = ws + 2 * nd;
    float* vbuf = ws + 3 * nd;
    float* sbuf = ws + 4 * nd;
    float4* meta = (float4*)(ws + 5 * nd);           // E float4
    int* deg    = (int*)(ws + 5 * nd + 4 * (size_t)E);
    int* off    = deg + N;                            // N+1
    int* cursor = off + N + 1;                        // N

    int gemm_gx = (N + 63) / 64;
    int edge_gx = (E + 255) / 256;
    int attn_gx = (N + 3) / 4;

    // ---- CSR build (once per call) ----
    hipMemsetAsync(deg, 0, (size_t)N * sizeof(int), stream);
    count_deg<<<edge_gx, 256, 0, stream>>>(ei, deg, E);
    scan_kernel<<<1, 1024, 0, stream>>>(deg, off, cursor, N);
    scatter_edges<<<edge_gx, 256, 0, stream>>>(ei, ea, cursor, meta, E);

    for (int l = 0; l < 3; ++l) {
        const float* cur = (l == 0) ? x : hbuf;
        const float* Wel = We + (size_t)l * 2 * HD;

        gemm4_128<<<dim3(gemm_gx, 4), 256, 0, stream>>>(
            cur,
            Wq + (size_t)l * HD * HD, Wk + (size_t)l * HD * HD,
            Wv + (size_t)l * HD * HD, Ws + (size_t)l * HD * HD,
            bq + (size_t)l * HD, bk + (size_t)l * HD,
            bv + (size_t)l * HD, bs + (size_t)l * HD,
            qbuf, kbuf, vbuf, sbuf, N);

        fused_attn<<<attn_gx, 256, 0, stream>>>(
            qbuf, kbuf, vbuf, sbuf, off, meta, Wel, hbuf, N);
    }

    // head: emb = leaky(h@W1+b1) -> reuse kbuf; logits+log_softmax -> d_out
    emb_kernel<<<(N * CC + 255) / 256, 256, 0, stream>>>(hbuf, W1, b1, kbuf, N);
    logits_kernel<<<(N * 8 + 255) / 256, 256, 0, stream>>>(kbuf, W2, b2, (float*)d_out, N);
}

// Round 5
// 751.628 us; speedup vs baseline: 2.6161x; 1.0363x over previous
//
#include <hip/hip_runtime.h>
#include <hip/hip_bf16.h>
#include <math.h>

#define HD 128   // hidden dim = H*C
#define NH 4     // heads
#define CC 32    // channels per head

typedef __attribute__((ext_vector_type(8))) short short8;
typedef __attribute__((ext_vector_type(4))) float f32x4;

__device__ __forceinline__ float leaky(float x) { return x > 0.f ? x : 0.01f * x; }

// f32 -> bf16 round-to-nearest-even (finite values)
__device__ __forceinline__ ushort bf16_rne(float f) {
    unsigned u = __float_as_uint(f);
    return (ushort)((u + 0x7fffu + ((u >> 16) & 1u)) >> 16);
}
__device__ __forceinline__ float bf16_f(ushort h) {
    return __uint_as_float(((unsigned)h) << 16);
}

// Wfrag layout: [mg(12)][ct(8)][kk(4)][lane(64)][j(8)] ushort, hi half then lo
// half at +WFRAG_HALF. mg = layer*4 + mat. B-frag mapping (16x16x32):
// col = ct*16+(lane&15), k = kk*32+(lane>>4)*8+j.
#define WFRAG_HALF (12 * 32 * 64 * 8)

// ---------------------------------------------------------------------------
// Convert W (f32, [3][128][128] x 4 matrices) into bf16 hi/lo B-fragments.
// One thread per (mg, ct, kk, lane): reads 8 strided f32, writes 16B hi + 16B lo.
// ---------------------------------------------------------------------------
__global__ __launch_bounds__(256) void conv_w(
    const float* __restrict__ Wq, const float* __restrict__ Wk,
    const float* __restrict__ Wv, const float* __restrict__ Wsk,
    ushort* __restrict__ frag)
{
    int tid = blockIdx.x * 256 + threadIdx.x;
    if (tid >= 12 * 8 * 4 * 64) return;
    int lane = tid & 63;
    int kk = (tid >> 6) & 3;
    int ct = (tid >> 8) & 7;
    int mg = tid >> 11;            // 0..11
    int l = mg >> 2, m = mg & 3;
    const float* src = ((m == 0) ? Wq : (m == 1) ? Wk : (m == 2) ? Wv : Wsk)
                       + (size_t)l * HD * HD;
    int col = ct * 16 + (lane & 15);
    int k0 = kk * 32 + (lane >> 4) * 8;
    ushort* dst = frag + (size_t)tid * 8;
#pragma unroll
    for (int j = 0; j < 8; ++j) {
        float w = src[(size_t)(k0 + j) * HD + col];
        ushort h = bf16_rne(w);
        dst[j] = h;
        dst[WFRAG_HALF + j] = bf16_rne(w - bf16_f(h));
    }
}

// ---------------------------------------------------------------------------
// MFMA GEMM via split-bf16 (3 passes: hh + hl + lh):
// O = X @ W + b for matrix blockIdx.y of layer `layer`. 64 rows/block,
// 4 waves; wave w -> rows w*16..w*16+15, all 128 cols (8 col-tiles).
// X tile converted to hi/lo bf16 in XOR-swizzled LDS; W frags precomputed.
// ---------------------------------------------------------------------------
__global__ __launch_bounds__(256) void gemm4_mfma(
    const float* __restrict__ X, const ushort* __restrict__ Wfrag,
    const float* __restrict__ bq, const float* __restrict__ bk,
    const float* __restrict__ bv, const float* __restrict__ bsk,
    float* __restrict__ Oq, float* __restrict__ Ok,
    float* __restrict__ Ov, float* __restrict__ Osk,
    int layer, int N)
{
    __shared__ __align__(16) ushort Xh[64 * HD];
    __shared__ __align__(16) ushort Xl[64 * HD];

    int mat = blockIdx.y;
    const float* b = (mat == 0) ? bq : (mat == 1) ? bk : (mat == 2) ? bv : bsk;
    float* O = (mat == 0) ? Oq : (mat == 1) ? Ok : (mat == 2) ? Ov : Osk;
    int mg = layer * 4 + mat;

    int t = threadIdx.x;
    int row0 = blockIdx.x * 64;

    // ---- stage X tile as hi/lo bf16, swizzled: byte ^= (row&7)<<4 ----
#pragma unroll
    for (int i = 0; i < 8; ++i) {
        int idx = t + i * 256;           // 0..2047
        int r = idx >> 5;                // 0..63
        int c4 = (idx & 31) * 4;         // first k of this float4
        int gr = row0 + r;
        float4 xv = (gr < N) ? *(const float4*)(X + (size_t)gr * HD + c4)
                             : make_float4(0.f, 0.f, 0.f, 0.f);
        ushort h0 = bf16_rne(xv.x), h1 = bf16_rne(xv.y),
               h2 = bf16_rne(xv.z), h3 = bf16_rne(xv.w);
        ushort l0 = bf16_rne(xv.x - bf16_f(h0)), l1 = bf16_rne(xv.y - bf16_f(h1)),
               l2 = bf16_rne(xv.z - bf16_f(h2)), l3 = bf16_rne(xv.w - bf16_f(h3));
        int off = r * 256 + c4 * 2;                 // byte offset, 8B-aligned
        int swz = off ^ ((r & 7) << 4);
        *(ushort4*)((char*)Xh + swz) = make_ushort4(h0, h1, h2, h3);
        *(ushort4*)((char*)Xl + swz) = make_ushort4(l0, l1, l2, l3);
    }
    __syncthreads();

    int wv = t >> 6;
    int lane = t & 63;
    int arow = wv * 16 + (lane & 15);      // A row = output row (lane&15)
    int abase = arow * 256;
    int aswz = (arow & 7) << 4;

    f32x4 acc[8];
#pragma unroll
    for (int ct = 0; ct < 8; ++ct) acc[ct] = (f32x4){0.f, 0.f, 0.f, 0.f};

#pragma unroll
    for (int kk = 0; kk < 4; ++kk) {
        int koff = abase + kk * 64 + (lane >> 4) * 16;   // bytes; k=(lane>>4)*8+j
        short8 ah = *(const short8*)((const char*)Xh + (koff ^ aswz));
        short8 al = *(const short8*)((const char*)Xl + (koff ^ aswz));
#pragma unroll
        for (int ct = 0; ct < 8; ++ct) {
            const ushort* wp = Wfrag + ((size_t)((mg * 8 + ct) * 4 + kk) * 64 + lane) * 8;
            short8 bh = *(const short8*)wp;
            short8 bl = *(const short8*)(wp + WFRAG_HALF);
            acc[ct] = __builtin_amdgcn_mfma_f32_16x16x32_bf16(ah, bh, acc[ct], 0, 0, 0);
            acc[ct] = __builtin_amdgcn_mfma_f32_16x16x32_bf16(ah, bl, acc[ct], 0, 0, 0);
            acc[ct] = __builtin_amdgcn_mfma_f32_16x16x32_bf16(al, bh, acc[ct], 0, 0, 0);
        }
    }

    // ---- epilogue: C/D col=lane&15, row=(lane>>4)*4+reg (m89-verified) ----
    int orow0 = row0 + wv * 16 + (lane >> 4) * 4;
    int col16 = lane & 15;
#pragma unroll
    for (int ct = 0; ct < 8; ++ct) {
        float bcol = b[ct * 16 + col16];
#pragma unroll
        for (int i = 0; i < 4; ++i) {
            int r = orow0 + i;
            if (r < N) O[(size_t)r * HD + ct * 16 + col16] = acc[ct][i] + bcol;
        }
    }
}

// ---------------------------------------------------------------------------
// CSR build step 1: deg[dst]++ per edge
// ---------------------------------------------------------------------------
__global__ __launch_bounds__(256) void count_deg(
    const int* __restrict__ ei, int* __restrict__ deg, int E)
{
    int e = blockIdx.x * 256 + threadIdx.x;
    if (e < E) atomicAdd(&deg[ei[E + e]], 1);
}

// ---------------------------------------------------------------------------
// CSR build step 2: exclusive scan of deg -> off (N+1), duplicate into cursor.
// ---------------------------------------------------------------------------
__global__ __launch_bounds__(1024) void scan_kernel(
    const int* __restrict__ deg, int* __restrict__ off,
    int* __restrict__ cursor, int N)
{
    __shared__ int wsum[16];
    __shared__ int carry_s;
    int tid = threadIdx.x;
    int lane = tid & 63;
    int w = tid >> 6;
    if (tid == 0) carry_s = 0;
    __syncthreads();
    for (int base = 0; base < N; base += 1024) {
        int idx = base + tid;
        int x = (idx < N) ? deg[idx] : 0;
        int val = x;
#pragma unroll
        for (int s = 1; s < 64; s <<= 1) {
            int t = __shfl_up(val, s);
            if (lane >= s) val += t;
        }
        if (lane == 63) wsum[w] = val;
        __syncthreads();
        if (w == 0) {
            int t = (lane < 16) ? wsum[lane] : 0;
#pragma unroll
            for (int s = 1; s < 16; s <<= 1) {
                int u = __shfl_up(t, s);
                if (lane >= s) t += u;
            }
            if (lane < 16) wsum[lane] = t;  // inclusive wave totals
        }
        __syncthreads();
        int carry = carry_s;
        int wexcl = (w > 0) ? wsum[w - 1] : 0;
        int excl = carry + wexcl + (val - x);
        if (idx < N) { off[idx] = excl; cursor[idx] = excl; }
        __syncthreads();
        if (tid == 0) carry_s = carry + wsum[15];
        __syncthreads();
    }
    if (threadIdx.x == 0) off[N] = carry_s;
}

// ---------------------------------------------------------------------------
// CSR build step 3: scatter edge meta {src, ea0, ea1} into dst-grouped slots
// ---------------------------------------------------------------------------
__global__ __launch_bounds__(256) void scatter_edges(
    const int* __restrict__ ei, const float* __restrict__ ea,
    int* __restrict__ cursor, float4* __restrict__ meta, int E)
{
    int e = blockIdx.x * 256 + threadIdx.x;
    if (e >= E) return;
    int dst = ei[E + e];
    int pos = atomicAdd(&cursor[dst], 1);
    meta[pos] = make_float4(__int_as_float(ei[e]), ea[2 * e], ea[2 * e + 1], 0.f);
}

// ---------------------------------------------------------------------------
// Flash-style fused attention: one wave per dst node. Online softmax over the
// node's incoming edges; no atomics, no alpha materialization. Epilogue fuses
// skip + leakyReLU. lane -> 2 channels (c = 2*lane), head = lane>>4.
// ---------------------------------------------------------------------------
__global__ __launch_bounds__(256) void fused_attn(
    const float* __restrict__ q, const float* __restrict__ k,
    const float* __restrict__ v, const float* __restrict__ skip,
    const int* __restrict__ off, const float4* __restrict__ meta,
    const float* __restrict__ We, float* __restrict__ hout, int N)
{
    int wid = (int)((blockIdx.x * 256 + threadIdx.x) >> 6);  // dst node
    int lane = threadIdx.x & 63;
    if (wid >= N) return;
    int c = lane * 2;

    float2 w0 = *(const float2*)(We + c);        // We row 0, this lane's 2 cols
    float2 w1 = *(const float2*)(We + HD + c);   // We row 1
    float2 q2 = *(const float2*)(q + (size_t)wid * HD + c);

    float m = -INFINITY, s = 0.f;
    float ox = 0.f, oy = 0.f;

    int beg = off[wid], end = off[wid + 1];
    for (int j = beg; j < end; ++j) {
        float4 md = meta[j];                      // broadcast (uniform addr)
        int src = __float_as_int(md.x);
        float ex = md.y * w0.x + md.z * w1.x;
        float ey = md.y * w0.y + md.z * w1.y;
        float2 kv = *(const float2*)(k + (size_t)src * HD + c);
        float2 vv = *(const float2*)(v + (size_t)src * HD + c);
        float p = q2.x * (kv.x + ex) + q2.y * (kv.y + ey);
        p += __shfl_xor(p, 1);
        p += __shfl_xor(p, 2);
        p += __shfl_xor(p, 4);
        p += __shfl_xor(p, 8);
        p *= 0.17677669529663687f;               // 1/sqrt(32)
        float mn = fmaxf(m, p);
        float scale = __expf(m - mn);            // first iter: exp(-inf)=0
        float pe = __expf(p - mn);
        s = s * scale + pe;
        ox = ox * scale + pe * (vv.x + ex);
        oy = oy * scale + pe * (vv.y + ey);
        m = mn;
    }

    float inv = 1.f / (s + 1e-16f);              // deg==0: o=0 -> skip only
    float2 sk = *(const float2*)(skip + (size_t)wid * HD + c);
    float2 hv;
    hv.x = leaky(ox * inv + sk.x);
    hv.y = leaky(oy * inv + sk.y);
    *(float2*)(hout + (size_t)wid * HD + c) = hv;
}

// ---------------------------------------------------------------------------
// emb = leaky(h @ W1 + b1)   (N x 128 @ 128 x 32)
// ---------------------------------------------------------------------------
__global__ __launch_bounds__(256) void emb_kernel(
    const float* __restrict__ h, const float* __restrict__ W1,
    const float* __restrict__ b1, float* __restrict__ emb, int N)
{
    int i = blockIdx.x * 256 + threadIdx.x;
    if (i >= N * CC) return;
    int row = i >> 5, col = i & 31;
    const float* hr = h + (size_t)row * HD;
    float acc = 0.f;
#pragma unroll 4
    for (int k = 0; k < HD; ++k) acc += hr[k] * W1[k * CC + col];
    emb[i] = leaky(acc + b1[col]);
}

// ---------------------------------------------------------------------------
// logits = emb @ W2 + b2; out = log_softmax(logits) per row (8 cols).
// ---------------------------------------------------------------------------
__global__ __launch_bounds__(256) void logits_kernel(
    const float* __restrict__ emb, const float* __restrict__ W2,
    const float* __restrict__ b2, float* __restrict__ out, int N)
{
    int i = blockIdx.x * 256 + threadIdx.x;
    int row = i >> 3, col = i & 7;
    if (row >= N) return;
    const float* er = emb + (size_t)row * CC;
    float acc = b2[col];
#pragma unroll
    for (int k = 0; k < CC; ++k) acc += er[k] * W2[k * 8 + col];
    float mx = acc;
    mx = fmaxf(mx, __shfl_xor(mx, 1));
    mx = fmaxf(mx, __shfl_xor(mx, 2));
    mx = fmaxf(mx, __shfl_xor(mx, 4));
    float ex = expf(acc - mx);
    float sm = ex;
    sm += __shfl_xor(sm, 1);
    sm += __shfl_xor(sm, 2);
    sm += __shfl_xor(sm, 4);
    out[i] = acc - mx - logf(sm);
}

extern "C" void kernel_launch(void* const* d_in, const int* in_sizes, int n_in,
                              void* d_out, int out_size, void* d_ws, size_t ws_size,
                              hipStream_t stream)
{
    const float* x  = (const float*)d_in[0];
    const int*   ei = (const int*)d_in[1];
    const float* ea = (const float*)d_in[2];
    const float* Wq = (const float*)d_in[3];
    const float* bq = (const float*)d_in[4];
    const float* Wk = (const float*)d_in[5];
    const float* bk = (const float*)d_in[6];
    const float* Wv = (const float*)d_in[7];
    const float* bv = (const float*)d_in[8];
    const float* We = (const float*)d_in[9];
    const float* Ws = (const float*)d_in[10];
    const float* bs = (const float*)d_in[11];
    const float* W1 = (const float*)d_in[12];
    const float* b1 = (const float*)d_in[13];
    const float* W2 = (const float*)d_in[14];
    const float* b2 = (const float*)d_in[15];

    int N = in_sizes[0] / HD;
    int E = in_sizes[1] / 2;

    float* ws = (float*)d_ws;
    size_t nd = (size_t)N * HD;
    float* hbuf = ws;
    float* qbuf = ws + nd;
    float* kbuf = ws + 2 * nd;
    float* vbuf = ws + 3 * nd;
    float* sbuf = ws + 4 * nd;
    float4* meta = (float4*)(ws + 5 * nd);           // E float4
    int* deg    = (int*)(ws + 5 * nd + 4 * (size_t)E);
    int* off    = deg + N;                            // N+1
    int* cursor = off + N + 1;                        // N
    size_t frag_byte = (((5 * nd + 4 * (size_t)E) + (size_t)(3 * N + 1)) * 4 + 15)
                       & ~(size_t)15;
    ushort* Wfrag = (ushort*)((char*)d_ws + frag_byte);

    int gemm_gx = (N + 63) / 64;
    int edge_gx = (E + 255) / 256;
    int attn_gx = (N + 3) / 4;

    // ---- CSR build + weight fragment conversion (once per call) ----
    hipMemsetAsync(deg, 0, (size_t)N * sizeof(int), stream);
    count_deg<<<edge_gx, 256, 0, stream>>>(ei, deg, E);
    scan_kernel<<<1, 1024, 0, stream>>>(deg, off, cursor, N);
    scatter_edges<<<edge_gx, 256, 0, stream>>>(ei, ea, cursor, meta, E);
    conv_w<<<(12 * 8 * 4 * 64 + 255) / 256, 256, 0, stream>>>(Wq, Wk, Wv, Ws, Wfrag);

    for (int l = 0; l < 3; ++l) {
        const float* cur = (l == 0) ? x : hbuf;
        const float* Wel = We + (size_t)l * 2 * HD;

        gemm4_mfma<<<dim3(gemm_gx, 4), 256, 0, stream>>>(
            cur, Wfrag,
            bq + (size_t)l * HD, bk + (size_t)l * HD,
            bv + (size_t)l * HD, bs + (size_t)l * HD,
            qbuf, kbuf, vbuf, sbuf, l, N);

        fused_attn<<<attn_gx, 256, 0, stream>>>(
            qbuf, kbuf, vbuf, sbuf, off, meta, Wel, hbuf, N);
    }

    // head: emb = leaky(h@W1+b1) -> reuse kbuf; logits+log_softmax -> d_out
    emb_kernel<<<(N * CC + 255) / 256, 256, 0, stream>>>(hbuf, W1, b1, kbuf, N);
    logits_kernel<<<(N * 8 + 255) / 256, 256, 0, stream>>>(kbuf, W2, b2, (float*)d_out, N);
}